// Round 5
// baseline (452.474 us; speedup 1.0000x reference)
//
#include <hip/hip_runtime.h>
#include <hip/hip_bf16.h>
#include <math.h>

#define B_DIM 64
#define T_DIM 512
#define D_DIM 1024
#define TT (T_DIM * T_DIM)   // 262144
#define TD (T_DIM * D_DIM)   // 524288

typedef _Float16 f16;
typedef f16 f16x4 __attribute__((ext_vector_type(4)));
typedef f16 f16x8 __attribute__((ext_vector_type(8)));
typedef float f32x4 __attribute__((ext_vector_type(4)));

// ===========================================================================
// FP16 MFMA path — 256x256 tile, BK=32, 8 waves, double-buffered LDS
// ===========================================================================

__device__ __forceinline__ void gld_lds16(const void* g, void* l) {
    __builtin_amdgcn_global_load_lds(
        (const __attribute__((address_space(1))) void*)g,
        (__attribute__((address_space(3))) void*)l, 16, 0, 0);
}

// swizzle: LDS[r][j] holds global k-chunk (j ^ ((r>>1)&3)).
// Per read-octet (8 lanes, consecutive rows, 16B each) this covers all 32
// banks exactly once -> conflict-free ds_read_b128 (old r&3 variant was 4-way).
#define SWZ(r) (((r) >> 1) & 3)

// C[M][N] = A[M][K] @ Bt[N][K]^T.  Tile 256x256, BK=32.
// 512 threads = 8 waves as 2(M)x4(N); per wave 128x64 = 8x4 frags of 16x16x32.
// EPI: 0 = f16 out (qU)
//      1 = f32 out + relu (att) + fused row/col softmax partials -> rowP/colP
//      2 = f32 out * 1/S where S merged from partial pair (scaleP[row], +pstr)
//          dual-operand (bz>=zsplit selects set 2)
template <int EPI>
__global__ __launch_bounds__(512, 2) void k_mfma2(
        const f16* __restrict__ A, int lda,
        const f16* __restrict__ Bt, int ldb, int K,
        void* __restrict__ Cout, int ldc,
        const float2* __restrict__ scaleP,
        long batchA, long batchB, long batchC,
        float2* __restrict__ rowP, float2* __restrict__ colP, long pstr,
        const f16* __restrict__ A2, const f16* __restrict__ Bt2,
        void* __restrict__ Cout2, const float2* __restrict__ scaleP2, int zsplit) {
    __shared__ f16 LA[2][8192];   // 2 x 16KB
    __shared__ f16 LB[2][8192];

    const int tid = threadIdx.x;
    const int lane = tid & 63, w = tid >> 6;

    // bijective XCD swizzle over the flattened grid (m204)
    const int gX = gridDim.x, gY = gridDim.y;
    int nwg = gX * gY * gridDim.z;
    int o = blockIdx.x + gX * (blockIdx.y + gY * blockIdx.z);
    int q8 = nwg >> 3, r8 = nwg & 7, xcd = o & 7, idx = o >> 3;
    int fl = (xcd < r8 ? xcd * (q8 + 1) : r8 * (q8 + 1) + (xcd - r8) * q8) + idx;
    const int bx = fl % gX;
    int tmp = fl / gX;
    const int by = tmp % gY;
    const int bz = tmp / gY;

    // dual-operand select (merged align GEMMs)
    const f16* Au = A; const f16* Bu = Bt;
    void* Cu = Cout; const float2* su = scaleP;
    int zb = bz;
    if constexpr (EPI == 2) {
        if (bz >= zsplit) {
            zb = bz - zsplit;
            Au = A2; Bu = Bt2; Cu = Cout2; su = scaleP2;
        }
    }

    const f16* Ab = Au + (long)zb * batchA + (long)(by * 256) * lda;
    const f16* Bb = Bu + (long)zb * batchB + (long)(bx * 256) * ldb;

    // staging decode: chunks ch0=tid, ch1=512+tid ; global slot = j ^ SWZ(row)
    const int r0 = tid >> 2, s0 = (tid & 3) ^ SWZ(r0);
    const int r1 = (512 + tid) >> 2, s1 = ((512 + tid) & 3) ^ SWZ(r1);
    const long offA0 = (long)r0 * lda + s0 * 8;
    const long offA1 = (long)r1 * lda + s1 * 8;
    const long offB0 = (long)r0 * ldb + s0 * 8;
    const long offB1 = (long)r1 * ldb + s1 * 8;
    const int ldsOff0 = w * 512;          // elems; DMA adds lane*16B
    const int ldsOff1 = 4096 + w * 512;

    const int g = lane >> 4;
    const int rA0 = (w & 1) * 128 + (lane & 15);
    const int rB0 = (w >> 1) * 64 + (lane & 15);

    f32x4 acc[8][4] = {};

    gld_lds16(Ab + offA0, &LA[0][ldsOff0]);
    gld_lds16(Ab + offA1, &LA[0][ldsOff1]);
    gld_lds16(Bb + offB0, &LB[0][ldsOff0]);
    gld_lds16(Bb + offB1, &LB[0][ldsOff1]);
    __syncthreads();

    const int NT = K >> 5;
    for (int t = 0; t < NT; ++t) {
        const int cur = t & 1;
        if (t + 1 < NT) {
            const long kt = (long)(t + 1) << 5;
            gld_lds16(Ab + offA0 + kt, &LA[cur ^ 1][ldsOff0]);
            gld_lds16(Ab + offA1 + kt, &LA[cur ^ 1][ldsOff1]);
            gld_lds16(Bb + offB0 + kt, &LB[cur ^ 1][ldsOff0]);
            gld_lds16(Bb + offB1 + kt, &LB[cur ^ 1][ldsOff1]);
        }
        f16x8 a[8], b[4];
#pragma unroll
        for (int m = 0; m < 8; ++m) {
            int r = rA0 + m * 16;
            a[m] = *(const f16x8*)(&LA[cur][r * 32 + ((g ^ SWZ(r)) << 3)]);
        }
#pragma unroll
        for (int n = 0; n < 4; ++n) {
            int r = rB0 + n * 16;
            b[n] = *(const f16x8*)(&LB[cur][r * 32 + ((g ^ SWZ(r)) << 3)]);
        }
#pragma unroll
        for (int m = 0; m < 8; ++m)
#pragma unroll
            for (int n = 0; n < 4; ++n)
                acc[m][n] = __builtin_amdgcn_mfma_f32_16x16x32_f16(a[m], b[n], acc[m][n], 0, 0, 0);
        __syncthreads();
    }

    const int row0 = by * 256 + (w & 1) * 128 + (lane >> 4) * 4;
    const int col0 = bx * 256 + (w >> 1) * 64 + (lane & 15);

    if constexpr (EPI == 0) {
        f16* C = (f16*)Cu;
#pragma unroll
        for (int m = 0; m < 8; ++m)
#pragma unroll
            for (int r = 0; r < 4; ++r) {
                long row = row0 + m * 16 + r;
#pragma unroll
                for (int n = 0; n < 4; ++n)
                    C[row * ldc + col0 + n * 16] = (f16)acc[m][n][r];
            }
    } else if constexpr (EPI == 1) {
#pragma unroll
        for (int m = 0; m < 8; ++m)
#pragma unroll
            for (int n = 0; n < 4; ++n)
#pragma unroll
                for (int r = 0; r < 4; ++r)
                    acc[m][n][r] = fmaxf(acc[m][n][r], 0.0f);
        float* C = (float*)Cu + (long)zb * batchC;
#pragma unroll
        for (int m = 0; m < 8; ++m)
#pragma unroll
            for (int r = 0; r < 4; ++r) {
                long row = row0 + m * 16 + r;
#pragma unroll
                for (int n = 0; n < 4; ++n)
                    C[row * ldc + col0 + n * 16] = acc[m][n][r];
            }
        // ---- fused softmax partials (reuse LA as scratch) ----
        float* redR = (float*)(&LA[0][0]);   // [2][128][4][2]
        float* redC = redR + 2048;           // [2][256][2]
        const int h = w & 1, cw = w >> 1;
#pragma unroll
        for (int m = 0; m < 8; ++m)
#pragma unroll
            for (int r = 0; r < 4; ++r) {
                float mx = fmaxf(fmaxf(acc[m][0][r], acc[m][1][r]),
                                 fmaxf(acc[m][2][r], acc[m][3][r]));
                mx = fmaxf(mx, __shfl_xor(mx, 1));
                mx = fmaxf(mx, __shfl_xor(mx, 2));
                mx = fmaxf(mx, __shfl_xor(mx, 4));
                mx = fmaxf(mx, __shfl_xor(mx, 8));
                float sm = __expf(acc[m][0][r] - mx) + __expf(acc[m][1][r] - mx)
                         + __expf(acc[m][2][r] - mx) + __expf(acc[m][3][r] - mx);
                sm += __shfl_xor(sm, 1);
                sm += __shfl_xor(sm, 2);
                sm += __shfl_xor(sm, 4);
                sm += __shfl_xor(sm, 8);
                if ((lane & 15) == 0) {
                    int lr = m * 16 + (lane >> 4) * 4 + r;
                    redR[((h * 128 + lr) * 4 + cw) * 2 + 0] = mx;
                    redR[((h * 128 + lr) * 4 + cw) * 2 + 1] = sm;
                }
            }
#pragma unroll
        for (int n = 0; n < 4; ++n) {
            float mx = acc[0][n][0];
#pragma unroll
            for (int m = 0; m < 8; ++m)
#pragma unroll
                for (int r = 0; r < 4; ++r) mx = fmaxf(mx, acc[m][n][r]);
            mx = fmaxf(mx, __shfl_xor(mx, 16));
            mx = fmaxf(mx, __shfl_xor(mx, 32));
            float sm = 0.f;
#pragma unroll
            for (int m = 0; m < 8; ++m)
#pragma unroll
                for (int r = 0; r < 4; ++r) sm += __expf(acc[m][n][r] - mx);
            sm += __shfl_xor(sm, 16);
            sm += __shfl_xor(sm, 32);
            if (lane < 16) {
                int c = cw * 64 + n * 16 + lane;
                redC[(h * 256 + c) * 2 + 0] = mx;
                redC[(h * 256 + c) * 2 + 1] = sm;
            }
        }
        __syncthreads();
        if (tid < 256) {
            float M = -1e30f, S = 0.f;
#pragma unroll
            for (int i = 0; i < 4; ++i) {
                float m_ = redR[(tid * 4 + i) * 2 + 0];
                float s_ = redR[(tid * 4 + i) * 2 + 1];
                float nm = fmaxf(M, m_);
                S = S * __expf(M - nm) + s_ * __expf(m_ - nm);
                M = nm;
            }
            rowP[(long)bx * pstr + (long)bz * 512 + by * 256 + tid] = make_float2(M, S);
        } else {
            int c = tid - 256;
            float m0_ = redC[c * 2 + 0], s0_ = redC[c * 2 + 1];
            float m1_ = redC[(256 + c) * 2 + 0], s1_ = redC[(256 + c) * 2 + 1];
            float M = fmaxf(m0_, m1_);
            float S = s0_ * __expf(m0_ - M) + s1_ * __expf(m1_ - M);
            colP[(long)by * pstr + (long)bz * 512 + bx * 256 + c] = make_float2(M, S);
        }
    } else {
        float* C = (float*)Cu + (long)zb * batchC;
        const float2* sp = su + (long)zb * 512;
#pragma unroll
        for (int m = 0; m < 8; ++m)
#pragma unroll
            for (int r = 0; r < 4; ++r) {
                long row = row0 + m * 16 + r;
                float2 pa = sp[row], pb = sp[pstr + row];
                float M = fmaxf(pa.x, pb.x);
                float S = pa.y * __expf(pa.x - M) + pb.y * __expf(pb.x - M);
                float inv = 1.0f / S;
#pragma unroll
                for (int n = 0; n < 4; ++n)
                    C[row * ldc + col0 + n * 16] = acc[m][n][r] * inv;
            }
    }
}

// cast both q tensors: z<64 -> q1, z>=64 -> q2. [B][T][D] f32 -> f16 + [B][D][T] f16
__global__ __launch_bounds__(256) void k_cast_both(const float* __restrict__ q1,
                                                   const float* __restrict__ q2,
                                                   f16* __restrict__ q1h, f16* __restrict__ q1ht,
                                                   f16* __restrict__ q2h, f16* __restrict__ q2ht) {
    __shared__ f16 tr[64][72];
    int zz = blockIdx.z;
    int b = zz & 63;
    const float* src = (zz < 64) ? q1 : q2;
    f16* dst  = (zz < 64) ? q1h : q2h;
    f16* dstT = (zz < 64) ? q1ht : q2ht;
    int d0 = blockIdx.x * 64, t0 = blockIdx.y * 64;
    const float* S = src + ((size_t)b * T_DIM + t0) * D_DIM + d0;
    f16* Dr = dst + ((size_t)b * T_DIM + t0) * D_DIM + d0;
    int tid = threadIdx.x;
    int rr = tid >> 4, cc = (tid & 15) * 4;
#pragma unroll
    for (int i = 0; i < 4; ++i) {
        int r = rr + i * 16;
        float4 v = *(const float4*)(S + (size_t)r * D_DIM + cc);
        f16x4 h = {(f16)v.x, (f16)v.y, (f16)v.z, (f16)v.w};
        *(f16x4*)(Dr + (size_t)r * D_DIM + cc) = h;
        tr[cc + 0][r] = h[0];
        tr[cc + 1][r] = h[1];
        tr[cc + 2][r] = h[2];
        tr[cc + 3][r] = h[3];
    }
    __syncthreads();
    f16* Dt = dstT + ((size_t)b * D_DIM + d0) * T_DIM + t0;
    int r2 = tid >> 3, c8 = (tid & 7) * 8;
#pragma unroll
    for (int i = 0; i < 2; ++i) {
        int d = r2 + i * 32;
        f16x8 vv = *(const f16x8*)(&tr[d][c8]);
        *(f16x8*)(Dt + (size_t)d * T_DIM + c8) = vv;
    }
}

// U [K=1024][N=1024] f32 -> Uht fp16 [N][K]
__global__ __launch_bounds__(256) void k_castU(const float* __restrict__ U,
                                               f16* __restrict__ Uht) {
    __shared__ f16 tr[64][72];
    int n0 = blockIdx.x * 64, k0 = blockIdx.y * 64;
    int tid = threadIdx.x;
    int rr = tid >> 4, cc = (tid & 15) * 4;
#pragma unroll
    for (int i = 0; i < 4; ++i) {
        int r = rr + i * 16;
        float4 v = *(const float4*)(U + (size_t)(k0 + r) * D_DIM + n0 + cc);
        tr[cc + 0][r] = (f16)v.x;
        tr[cc + 1][r] = (f16)v.y;
        tr[cc + 2][r] = (f16)v.z;
        tr[cc + 3][r] = (f16)v.w;
    }
    __syncthreads();
    int r2 = tid >> 3, c8 = (tid & 7) * 8;
#pragma unroll
    for (int i = 0; i < 2; ++i) {
        int n = r2 + i * 32;
        f16x8 vv = *(const f16x8*)(&tr[n][c8]);
        *(f16x8*)(Uht + (size_t)(n0 + n) * D_DIM + k0 + c8) = vv;
    }
}

// att f32 -> P2h[t][s] = exp(att - rmax[t]), P1h[s][t] = exp(att - cmax[s]);
// rmax/cmax merged inline from rowP/colP partial pairs.
__global__ __launch_bounds__(256) void k_pconv(const float* __restrict__ att,
                                               const float2* __restrict__ rowP,
                                               const float2* __restrict__ colP, long pstr,
                                               f16* __restrict__ P2, f16* __restrict__ P1) {
    __shared__ f16 tr[64][72];
    __shared__ float rmS[64], cmS[64];
    int z = blockIdx.z;
    int t0 = blockIdx.y * 64, s0 = blockIdx.x * 64;
    int tid = threadIdx.x;
    if (tid < 64) {
        float2 a = rowP[(long)z * 512 + t0 + tid];
        float2 b = rowP[pstr + (long)z * 512 + t0 + tid];
        rmS[tid] = fmaxf(a.x, b.x);
    } else if (tid < 128) {
        int s = tid - 64;
        float2 a = colP[(long)z * 512 + s0 + s];
        float2 b = colP[pstr + (long)z * 512 + s0 + s];
        cmS[s] = fmaxf(a.x, b.x);
    }
    __syncthreads();
    const float* S = att + (size_t)z * TT + (size_t)t0 * T_DIM + s0;
    int rr = tid >> 4, cc = (tid & 15) * 4;
#pragma unroll
    for (int i = 0; i < 4; ++i) {
        int r = rr + i * 16;
        float4 v = *(const float4*)(S + (size_t)r * T_DIM + cc);
        float m = rmS[r];
        f16x4 p2 = {(f16)__expf(v.x - m), (f16)__expf(v.y - m),
                    (f16)__expf(v.z - m), (f16)__expf(v.w - m)};
        *(f16x4*)(P2 + (size_t)z * TT + (size_t)(t0 + r) * T_DIM + s0 + cc) = p2;
        tr[cc + 0][r] = (f16)__expf(v.x - cmS[cc + 0]);
        tr[cc + 1][r] = (f16)__expf(v.y - cmS[cc + 1]);
        tr[cc + 2][r] = (f16)__expf(v.z - cmS[cc + 2]);
        tr[cc + 3][r] = (f16)__expf(v.w - cmS[cc + 3]);
    }
    __syncthreads();
    int r2 = tid >> 3, c8 = (tid & 7) * 8;
#pragma unroll
    for (int i = 0; i < 2; ++i) {
        int s = r2 + i * 32;
        f16x8 vv = *(const f16x8*)(&tr[s][c8]);
        *(f16x8*)(P1 + (size_t)z * TT + (size_t)(s0 + s) * T_DIM + t0 + c8) = vv;
    }
}

// ---------------------------------------------------------------------------
// standalone stats (fp32 fallback path only)
// ---------------------------------------------------------------------------
__global__ __launch_bounds__(256) void k_rowstats(const float* __restrict__ att,
                                                  float* __restrict__ rmax,
                                                  float* __restrict__ rsum, int b0) {
    int wave = threadIdx.x >> 6, lane = threadIdx.x & 63;
    int lr = blockIdx.x * 4 + wave;
    const float4* row = reinterpret_cast<const float4*>(att + (size_t)lr * T_DIM);
    float4 v0 = row[lane];
    float4 v1 = row[lane + 64];
    float m = fmaxf(fmaxf(fmaxf(v0.x, v0.y), fmaxf(v0.z, v0.w)),
                    fmaxf(fmaxf(v1.x, v1.y), fmaxf(v1.z, v1.w)));
#pragma unroll
    for (int off = 32; off >= 1; off >>= 1) m = fmaxf(m, __shfl_xor(m, off));
    float s = __expf(v0.x - m) + __expf(v0.y - m) + __expf(v0.z - m) + __expf(v0.w - m)
            + __expf(v1.x - m) + __expf(v1.y - m) + __expf(v1.z - m) + __expf(v1.w - m);
#pragma unroll
    for (int off = 32; off >= 1; off >>= 1) s += __shfl_xor(s, off);
    if (lane == 0) {
        size_t gr = (size_t)b0 * T_DIM + lr;
        rmax[gr] = m;
        rsum[gr] = s;
    }
}

__global__ __launch_bounds__(256) void k_colstats(const float* __restrict__ att,
                                                  float* __restrict__ cmax,
                                                  float* __restrict__ csum, int b0) {
    int lb = blockIdx.y;
    int s = blockIdx.x * 256 + threadIdx.x;
    const float* base = att + (size_t)lb * TT + s;
    float m = -INFINITY, sum = 0.f;
    for (int t = 0; t < T_DIM; ++t) {
        float x = base[(size_t)t * T_DIM];
        float nm = fmaxf(m, x);
        sum = sum * __expf(m - nm) + __expf(x - nm);
        m = nm;
    }
    size_t g = (size_t)(b0 + lb) * T_DIM + s;
    cmax[g] = m;
    csum[g] = sum;
}

// ===========================================================================
// FP32 fallback path — used only if ws too small
// ===========================================================================
#define BM 128
#define BN 128
#define BKK 16
#define APITCH 132

__device__ __forceinline__ void stage_a_rowmajor(float* As, const float* __restrict__ A,
                                                 int lda, int tid) {
#pragma unroll
    for (int i = 0; i < 2; ++i) {
        int idx = tid + i * 256;
        int r = idx >> 2;
        int k4 = (idx & 3) << 2;
        float4 v = *reinterpret_cast<const float4*>(&A[(size_t)r * lda + k4]);
        As[(k4 + 0) * APITCH + r] = v.x;
        As[(k4 + 1) * APITCH + r] = v.y;
        As[(k4 + 2) * APITCH + r] = v.z;
        As[(k4 + 3) * APITCH + r] = v.w;
    }
}
__device__ __forceinline__ void stage_a_rowmajor_exp(float* As, const float* __restrict__ A,
                                                     int lda, const float* __restrict__ rowmax,
                                                     int tid) {
#pragma unroll
    for (int i = 0; i < 2; ++i) {
        int idx = tid + i * 256;
        int r = idx >> 2;
        int k4 = (idx & 3) << 2;
        float4 v = *reinterpret_cast<const float4*>(&A[(size_t)r * lda + k4]);
        float m = rowmax[r];
        As[(k4 + 0) * APITCH + r] = __expf(v.x - m);
        As[(k4 + 1) * APITCH + r] = __expf(v.y - m);
        As[(k4 + 2) * APITCH + r] = __expf(v.z - m);
        As[(k4 + 3) * APITCH + r] = __expf(v.w - m);
    }
}
__device__ __forceinline__ void stage_a_colmajor_exp(float* As, const float* __restrict__ S,
                                                     int lds, const float* __restrict__ colmax,
                                                     int tid) {
#pragma unroll
    for (int i = 0; i < 2; ++i) {
        int idx = tid + i * 256;
        int k = idx >> 5;
        int m4 = (idx & 31) << 2;
        float4 v = *reinterpret_cast<const float4*>(&S[(size_t)k * lds + m4]);
        float4 c = *reinterpret_cast<const float4*>(&colmax[m4]);
        float4 o;
        o.x = __expf(v.x - c.x); o.y = __expf(v.y - c.y);
        o.z = __expf(v.z - c.z); o.w = __expf(v.w - c.w);
        *reinterpret_cast<float4*>(&As[k * APITCH + m4]) = o;
    }
}
__device__ __forceinline__ void stage_b_rowmajor(float* Bs, const float* __restrict__ Bp,
                                                 int ldb, int tid) {
#pragma unroll
    for (int i = 0; i < 2; ++i) {
        int idx = tid + i * 256;
        int k = idx >> 5;
        int c4 = idx & 31;
        float4 v = *reinterpret_cast<const float4*>(&Bp[(size_t)k * ldb + (c4 << 2)]);
        *reinterpret_cast<float4*>(&Bs[k * BN + ((c4 & 1) << 6) + ((c4 >> 1) << 2)]) = v;
    }
}
__device__ __forceinline__ void stage_b_transpose(float* Bs, const float* __restrict__ Q,
                                                  int ldq, int tid) {
#pragma unroll
    for (int i = 0; i < 2; ++i) {
        int idx = tid + i * 256;
        int s = idx >> 2;
        int e4 = (idx & 3) << 2;
        float4 v = *reinterpret_cast<const float4*>(&Q[(size_t)s * ldq + e4]);
        int sw = ((s & 4) << 4) + ((s >> 3) << 2) + (s & 3);
        Bs[(e4 + 0) * BN + sw] = v.x;
        Bs[(e4 + 1) * BN + sw] = v.y;
        Bs[(e4 + 2) * BN + sw] = v.z;
        Bs[(e4 + 3) * BN + sw] = v.w;
    }
}
__device__ __forceinline__ void gemm_inner(const float* As, const float* Bs,
                                           float acc[8][8], int tx, int ty) {
#pragma unroll
    for (int k = 0; k < BKK; ++k) {
        float4 a0 = *reinterpret_cast<const float4*>(&As[k * APITCH + ty * 8]);
        float4 a1 = *reinterpret_cast<const float4*>(&As[k * APITCH + ty * 8 + 4]);
        float4 b0 = *reinterpret_cast<const float4*>(&Bs[k * BN + tx * 4]);
        float4 b1 = *reinterpret_cast<const float4*>(&Bs[k * BN + 64 + tx * 4]);
        float a[8] = {a0.x, a0.y, a0.z, a0.w, a1.x, a1.y, a1.z, a1.w};
        float b[8] = {b0.x, b0.y, b0.z, b0.w, b1.x, b1.y, b1.z, b1.w};
#pragma unroll
        for (int i = 0; i < 8; ++i)
#pragma unroll
            for (int j = 0; j < 8; ++j)
                acc[i][j] = fmaf(a[i], b[j], acc[i][j]);
    }
}
__global__ __launch_bounds__(256) void k_gemm_qU(const float* __restrict__ q1,
                                                 const float* __restrict__ U,
                                                 float* __restrict__ qU, int b0) {
    __shared__ float As[BKK * APITCH];
    __shared__ float Bs[BKK * BN];
    int tid = threadIdx.x, tx = tid & 15, ty = tid >> 4;
    int m0 = blockIdx.y * BM;
    int n0 = blockIdx.x * BN;
    const float* Abase = q1 + (size_t)b0 * TD + (size_t)m0 * D_DIM;
    const float* Bbase = U + n0;
    float acc[8][8] = {};
    for (int kt = 0; kt < D_DIM; kt += BKK) {
        stage_a_rowmajor(As, Abase + kt, D_DIM, tid);
        stage_b_rowmajor(Bs, Bbase + (size_t)kt * D_DIM, D_DIM, tid);
        __syncthreads();
        gemm_inner(As, Bs, acc, tx, ty);
        __syncthreads();
    }
    float* Cp = qU + (size_t)m0 * D_DIM + n0;
#pragma unroll
    for (int i = 0; i < 8; ++i) {
        int r = ty * 8 + i;
        float4 o0 = {acc[i][0], acc[i][1], acc[i][2], acc[i][3]};
        float4 o1 = {acc[i][4], acc[i][5], acc[i][6], acc[i][7]};
        *reinterpret_cast<float4*>(&Cp[(size_t)r * D_DIM + tx * 8]) = o0;
        *reinterpret_cast<float4*>(&Cp[(size_t)r * D_DIM + tx * 8 + 4]) = o1;
    }
}
__global__ __launch_bounds__(256) void k_att(const float* __restrict__ qU,
                                             const float* __restrict__ q2,
                                             float* __restrict__ att, int b0) {
    __shared__ float As[BKK * APITCH];
    __shared__ float Bs[BKK * BN];
    int tid = threadIdx.x, tx = tid & 15, ty = tid >> 4;
    int lb = blockIdx.z;
    int m0 = blockIdx.y * BM;
    int n0 = blockIdx.x * BN;
    const float* Abase = qU + (size_t)lb * TD + (size_t)m0 * D_DIM;
    const float* Qbase = q2 + (size_t)(b0 + lb) * TD + (size_t)n0 * D_DIM;
    float acc[8][8] = {};
    for (int kt = 0; kt < D_DIM; kt += BKK) {
        stage_a_rowmajor(As, Abase + kt, D_DIM, tid);
        stage_b_transpose(Bs, Qbase + kt, D_DIM, tid);
        __syncthreads();
        gemm_inner(As, Bs, acc, tx, ty);
        __syncthreads();
    }
    float* Cp = att + (size_t)lb * TT + (size_t)m0 * T_DIM + n0;
#pragma unroll
    for (int i = 0; i < 8; ++i) {
        int r = ty * 8 + i;
        float4 o0 = {fmaxf(acc[i][0], 0.f), fmaxf(acc[i][1], 0.f), fmaxf(acc[i][2], 0.f), fmaxf(acc[i][3], 0.f)};
        float4 o1 = {fmaxf(acc[i][4], 0.f), fmaxf(acc[i][5], 0.f), fmaxf(acc[i][6], 0.f), fmaxf(acc[i][7], 0.f)};
        *reinterpret_cast<float4*>(&Cp[(size_t)r * T_DIM + tx * 8]) = o0;
        *reinterpret_cast<float4*>(&Cp[(size_t)r * T_DIM + tx * 8 + 4]) = o1;
    }
}
__global__ __launch_bounds__(256) void k_q2align(const float* __restrict__ att,
                                                 const float* __restrict__ q2,
                                                 const float* __restrict__ rmax,
                                                 const float* __restrict__ rsum,
                                                 float* __restrict__ out, int b0) {
    __shared__ float As[BKK * APITCH];
    __shared__ float Bs[BKK * BN];
    int tid = threadIdx.x, tx = tid & 15, ty = tid >> 4;
    int lb = blockIdx.z;
    int m0 = blockIdx.y * BM;
    int n0 = blockIdx.x * BN;
    const float* Abase = att + (size_t)lb * TT + (size_t)m0 * T_DIM;
    const float* rmaxp = rmax + (size_t)(b0 + lb) * T_DIM + m0;
    const float* rsump = rsum + (size_t)(b0 + lb) * T_DIM + m0;
    const float* Bbase = q2 + (size_t)(b0 + lb) * TD + n0;
    float acc[8][8] = {};
    for (int kt = 0; kt < T_DIM; kt += BKK) {
        stage_a_rowmajor_exp(As, Abase + kt, T_DIM, rmaxp, tid);
        stage_b_rowmajor(Bs, Bbase + (size_t)kt * D_DIM, D_DIM, tid);
        __syncthreads();
        gemm_inner(As, Bs, acc, tx, ty);
        __syncthreads();
    }
    float* Cp = out + (size_t)B_DIM * TD + (size_t)(b0 + lb) * TD + (size_t)m0 * D_DIM + n0;
#pragma unroll
    for (int i = 0; i < 8; ++i) {
        int r = ty * 8 + i;
        float inv = 1.0f / rsump[r];
        float4 o0 = {acc[i][0] * inv, acc[i][1] * inv, acc[i][2] * inv, acc[i][3] * inv};
        float4 o1 = {acc[i][4] * inv, acc[i][5] * inv, acc[i][6] * inv, acc[i][7] * inv};
        *reinterpret_cast<float4*>(&Cp[(size_t)r * D_DIM + tx * 8]) = o0;
        *reinterpret_cast<float4*>(&Cp[(size_t)r * D_DIM + tx * 8 + 4]) = o1;
    }
}
__global__ __launch_bounds__(256) void k_q1align(const float* __restrict__ att,
                                                 const float* __restrict__ q1,
                                                 const float* __restrict__ cmax,
                                                 const float* __restrict__ csum,
                                                 float* __restrict__ out, int b0) {
    __shared__ float As[BKK * APITCH];
    __shared__ float Bs[BKK * BN];
    int tid = threadIdx.x, tx = tid & 15, ty = tid >> 4;
    int lb = blockIdx.z;
    int m0 = blockIdx.y * BM;
    int n0 = blockIdx.x * BN;
    const float* Sbase = att + (size_t)lb * TT + m0;
    const float* cmaxp = cmax + (size_t)(b0 + lb) * T_DIM + m0;
    const float* csump = csum + (size_t)(b0 + lb) * T_DIM + m0;
    const float* Bbase = q1 + (size_t)(b0 + lb) * TD + n0;
    float acc[8][8] = {};
    for (int kt = 0; kt < T_DIM; kt += BKK) {
        stage_a_colmajor_exp(As, Sbase + (size_t)kt * T_DIM, T_DIM, cmaxp, tid);
        stage_b_rowmajor(Bs, Bbase + (size_t)kt * D_DIM, D_DIM, tid);
        __syncthreads();
        gemm_inner(As, Bs, acc, tx, ty);
        __syncthreads();
    }
    float* Cp = out + (size_t)(b0 + lb) * TD + (size_t)m0 * D_DIM + n0;
#pragma unroll
    for (int i = 0; i < 8; ++i) {
        int r = ty * 8 + i;
        float inv = 1.0f / csump[r];
        float4 o0 = {acc[i][0] * inv, acc[i][1] * inv, acc[i][2] * inv, acc[i][3] * inv};
        float4 o1 = {acc[i][4] * inv, acc[i][5] * inv, acc[i][6] * inv, acc[i][7] * inv};
        *reinterpret_cast<float4*>(&Cp[(size_t)r * D_DIM + tx * 8]) = o0;
        *reinterpret_cast<float4*>(&Cp[(size_t)r * D_DIM + tx * 8 + 4]) = o1;
    }
}

// ===========================================================================
extern "C" void kernel_launch(void* const* d_in, const int* in_sizes, int n_in,
                              void* d_out, int out_size, void* d_ws, size_t ws_size,
                              hipStream_t stream) {
    const float* q1 = (const float*)d_in[0];
    const float* q2 = (const float*)d_in[1];
    const float* U  = (const float*)d_in[2];
    float* out = (float*)d_out;

    const size_t BT  = (size_t)B_DIM * T_DIM;       // 32768
    const size_t BTD = (size_t)B_DIM * TD;          // 33.55M
    const size_t DD  = (size_t)D_DIM * D_DIM;       // 1.05M

    // ---- fp16 MFMA path sizing ----
    const size_t fixedB = (4 * BTD + DD) * 2;        // q1h,q1ht,q2h,q2ht,Uht fp16
    const size_t perbB  = (size_t)TD * 2 + (size_t)TT * 4 + (size_t)TT * 4
                        + 4ull * T_DIM * sizeof(float2);
    int C = 64;
    while (C > 1 && fixedB + (size_t)C * perbB > ws_size) C >>= 1;

    if (fixedB + perbB <= ws_size) {
        f16* q1h  = (f16*)d_ws;
        f16* q1ht = q1h  + BTD;
        f16* q2h  = q1ht + BTD;
        f16* q2ht = q2h  + BTD;
        f16* Uht  = q2ht + BTD;
        f16* qUh  = Uht  + DD;
        float* att = (float*)(qUh + (size_t)C * TD);
        f16* P2h  = (f16*)(att + (size_t)C * TT);
        f16* P1h  = P2h + (size_t)C * TT;
        float2* rowP = (float2*)(P1h + (size_t)C * TT);     // [2][C*512]
        float2* colP = rowP + 2ull * C * T_DIM;             // [2][C*512]
        const long pstr = (long)C * T_DIM;

        k_cast_both<<<dim3(16, 8, 128), 256, 0, stream>>>(q1, q2, q1h, q1ht, q2h, q2ht);
        k_castU<<<dim3(16, 16), 256, 0, stream>>>(U, Uht);

        for (int b0 = 0; b0 < B_DIM; b0 += C) {
            // qUh = q1h @ U   (M = C*512, N = K = 1024)
            k_mfma2<0><<<dim3(4, C * 2, 1), 512, 0, stream>>>(
                q1h + (size_t)b0 * TD, D_DIM, Uht, D_DIM, D_DIM,
                qUh, D_DIM, nullptr, 0, 0, 0,
                nullptr, nullptr, 0, nullptr, nullptr, nullptr, nullptr, 0);
            // att = relu(qUh @ q2^T) + fused softmax partials
            k_mfma2<1><<<dim3(2, 2, C), 512, 0, stream>>>(
                qUh, D_DIM, q2h + (size_t)b0 * TD, D_DIM, D_DIM,
                att, T_DIM, nullptr, (long)TD, (long)TD, (long)TT,
                rowP, colP, pstr, nullptr, nullptr, nullptr, nullptr, 0);
            // P conversion (merges partial stats inline)
            k_pconv<<<dim3(8, 8, C), 256, 0, stream>>>(att, rowP, colP, pstr, P2h, P1h);
            // merged align GEMMs: z<C -> q2_align (out 1, scale from rowP),
            //                     z>=C -> q1_align (out 0, scale from colP)
            k_mfma2<2><<<dim3(4, 2, 2 * C), 512, 0, stream>>>(
                P2h, T_DIM, q2ht + (size_t)b0 * TD, T_DIM, T_DIM,
                out + BTD + (size_t)b0 * TD, D_DIM, rowP,
                (long)TT, (long)TD, (long)TD,
                nullptr, nullptr, pstr,
                P1h, q1ht + (size_t)b0 * TD,
                out + (size_t)b0 * TD, colP, C);
        }
        return;
    }

    // ---- fp32 fallback ----
    const size_t statsElems = 4ull * B_DIM * T_DIM;
    float* rmax = (float*)d_ws;
    float* rsum = rmax + BT;
    float* cmax = rsum + BT;
    float* csum = cmax + BT;
    float* scratch = csum + BT;
    size_t availFloats = (ws_size > statsElems * 4) ? (ws_size - statsElems * 4) / 4 : 0;
    int C2 = 64;
    while (C2 > 1 && (size_t)C2 * (TD + TT) > availFloats) C2 >>= 1;
    if ((size_t)C2 * (TD + TT) > availFloats) return;
    float* qU  = scratch;
    float* att = qU + (size_t)C2 * TD;
    for (int b0 = 0; b0 < B_DIM; b0 += C2) {
        k_gemm_qU<<<dim3(D_DIM / BN, C2 * (T_DIM / BM)), 256, 0, stream>>>(q1, U, qU, b0);
        k_att<<<dim3(T_DIM / BN, T_DIM / BM, C2), 256, 0, stream>>>(qU, q2, att, b0);
        k_rowstats<<<dim3(C2 * T_DIM / 4), 256, 0, stream>>>(att, rmax, rsum, b0);
        k_colstats<<<dim3(T_DIM / 256, C2), 256, 0, stream>>>(att, cmax, csum, b0);
        k_q2align<<<dim3(D_DIM / BN, T_DIM / BM, C2), 256, 0, stream>>>(att, q2, rmax, rsum, out, b0);
        k_q1align<<<dim3(D_DIM / BN, T_DIM / BM, C2), 256, 0, stream>>>(att, q1, cmax, csum, out, b0);
    }
}

// Round 6
// 421.985 us; speedup vs baseline: 1.0723x; 1.0723x over previous
//
#include <hip/hip_runtime.h>
#include <hip/hip_bf16.h>
#include <math.h>

#define B_DIM 64
#define T_DIM 512
#define D_DIM 1024
#define TT (T_DIM * T_DIM)   // 262144
#define TD (T_DIM * D_DIM)   // 524288
#define PSTR ((long)B_DIM * T_DIM)  // 32768: stride between the 2 softmax partials

typedef _Float16 f16;
typedef f16 f16x4 __attribute__((ext_vector_type(4)));
typedef f16 f16x8 __attribute__((ext_vector_type(8)));
typedef float f32x4 __attribute__((ext_vector_type(4)));

__device__ __forceinline__ void gld_lds16(const void* g, void* l) {
    __builtin_amdgcn_global_load_lds(
        (const __attribute__((address_space(1))) void*)g,
        (__attribute__((address_space(3))) void*)l, 16, 0, 0);
}

// LDS[r][j] holds global k-chunk (j ^ ((r>>1)&3)); conflict-free ds_read_b128.
#define SWZ(r) (((r) >> 1) & 3)

// ===========================================================================
// Core MFMA GEMM: C[M][N] = A[M][K] @ Bt[N][K]^T, 256x256 tile, BK=32,
// 8 waves 2Mx4N, per-wave 128x64 = 8x4 frags of 16x16x32, dbuf LDS + gld_lds.
// EPI 1 = f32 out + relu + fused row/col softmax partials (att GEMM)
// EPI 2 = f32 out * 1/S, S merged from partial pair scaleP[row],[PSTR+row]
// ===========================================================================
template <int EPI>
__global__ __launch_bounds__(512, 2) void k_mfma2(
        const f16* __restrict__ A, int lda,
        const f16* __restrict__ Bt, int ldb, int K,
        void* __restrict__ Cout, int ldc,
        const float2* __restrict__ scaleP,
        long batchA, long batchB, long batchC,
        float2* __restrict__ rowP, float2* __restrict__ colP) {
    __shared__ __align__(16) f16 LA[2][8192];
    __shared__ __align__(16) f16 LB[2][8192];

    const int tid = threadIdx.x;
    const int lane = tid & 63, w = tid >> 6;

    // bijective XCD swizzle (nwg is a multiple of 8 for all our grids)
    const int gX = gridDim.x, gY = gridDim.y;
    int nwg = gX * gY * gridDim.z;
    int o = blockIdx.x + gX * (blockIdx.y + gY * blockIdx.z);
    int q8 = nwg >> 3;
    int fl = (o & 7) * q8 + (o >> 3);
    const int bx = fl % gX;
    int tmp = fl / gX;
    const int by = tmp % gY;
    const int bz = tmp / gY;

    const f16* Ab = A + (long)bz * batchA + (long)(by * 256) * lda;
    const f16* Bb = Bt + (long)bz * batchB + (long)(bx * 256) * ldb;

    const int r0 = tid >> 2, s0 = (tid & 3) ^ SWZ(r0);
    const int r1 = r0 + 128, s1 = (tid & 3) ^ SWZ(r1);
    const long offA0 = (long)r0 * lda + s0 * 8;
    const long offA1 = (long)r1 * lda + s1 * 8;
    const long offB0 = (long)r0 * ldb + s0 * 8;
    const long offB1 = (long)r1 * ldb + s1 * 8;
    const int ldsOff0 = w * 512;
    const int ldsOff1 = 4096 + w * 512;

    const int g = lane >> 4;
    const int rA0 = (w & 1) * 128 + (lane & 15);
    const int rB0 = (w >> 1) * 64 + (lane & 15);

    f32x4 acc[8][4] = {};

    gld_lds16(Ab + offA0, &LA[0][ldsOff0]);
    gld_lds16(Ab + offA1, &LA[0][ldsOff1]);
    gld_lds16(Bb + offB0, &LB[0][ldsOff0]);
    gld_lds16(Bb + offB1, &LB[0][ldsOff1]);
    __syncthreads();

    const int NT = K >> 5;
    for (int t = 0; t < NT; ++t) {
        const int cur = t & 1;
        if (t + 1 < NT) {
            const long kt = (long)(t + 1) << 5;
            gld_lds16(Ab + offA0 + kt, &LA[cur ^ 1][ldsOff0]);
            gld_lds16(Ab + offA1 + kt, &LA[cur ^ 1][ldsOff1]);
            gld_lds16(Bb + offB0 + kt, &LB[cur ^ 1][ldsOff0]);
            gld_lds16(Bb + offB1 + kt, &LB[cur ^ 1][ldsOff1]);
        }
        f16x8 a[8], b[4];
#pragma unroll
        for (int m = 0; m < 8; ++m) {
            int r = rA0 + m * 16;
            a[m] = *(const f16x8*)(&LA[cur][r * 32 + ((g ^ SWZ(r)) << 3)]);
        }
#pragma unroll
        for (int n = 0; n < 4; ++n) {
            int r = rB0 + n * 16;
            b[n] = *(const f16x8*)(&LB[cur][r * 32 + ((g ^ SWZ(r)) << 3)]);
        }
        __builtin_amdgcn_s_setprio(1);
#pragma unroll
        for (int m = 0; m < 8; ++m)
#pragma unroll
            for (int n = 0; n < 4; ++n)
                acc[m][n] = __builtin_amdgcn_mfma_f32_16x16x32_f16(a[m], b[n], acc[m][n], 0, 0, 0);
        __builtin_amdgcn_s_setprio(0);
        __syncthreads();
    }

    const int row0 = by * 256 + (w & 1) * 128 + (lane >> 4) * 4;
    const int col0 = bx * 256 + (w >> 1) * 64 + (lane & 15);

    if constexpr (EPI == 1) {
#pragma unroll
        for (int m = 0; m < 8; ++m)
#pragma unroll
            for (int n = 0; n < 4; ++n)
#pragma unroll
                for (int r = 0; r < 4; ++r)
                    acc[m][n][r] = fmaxf(acc[m][n][r], 0.0f);
        float* C = (float*)Cout + (long)bz * batchC;
#pragma unroll
        for (int m = 0; m < 8; ++m)
#pragma unroll
            for (int r = 0; r < 4; ++r) {
                long row = row0 + m * 16 + r;
#pragma unroll
                for (int n = 0; n < 4; ++n)
                    C[row * ldc + col0 + n * 16] = acc[m][n][r];
            }
        // fused softmax partials (reuse LA as scratch)
        float* redR = (float*)(&LA[0][0]);   // [2][128][4][2]
        float* redC = redR + 2048;           // [2][256][2]
        const int h = w & 1, cw = w >> 1;
#pragma unroll
        for (int m = 0; m < 8; ++m)
#pragma unroll
            for (int r = 0; r < 4; ++r) {
                float mx = fmaxf(fmaxf(acc[m][0][r], acc[m][1][r]),
                                 fmaxf(acc[m][2][r], acc[m][3][r]));
                mx = fmaxf(mx, __shfl_xor(mx, 1));
                mx = fmaxf(mx, __shfl_xor(mx, 2));
                mx = fmaxf(mx, __shfl_xor(mx, 4));
                mx = fmaxf(mx, __shfl_xor(mx, 8));
                float sm = __expf(acc[m][0][r] - mx) + __expf(acc[m][1][r] - mx)
                         + __expf(acc[m][2][r] - mx) + __expf(acc[m][3][r] - mx);
                sm += __shfl_xor(sm, 1);
                sm += __shfl_xor(sm, 2);
                sm += __shfl_xor(sm, 4);
                sm += __shfl_xor(sm, 8);
                if ((lane & 15) == 0) {
                    int lr = m * 16 + (lane >> 4) * 4 + r;
                    redR[((h * 128 + lr) * 4 + cw) * 2 + 0] = mx;
                    redR[((h * 128 + lr) * 4 + cw) * 2 + 1] = sm;
                }
            }
#pragma unroll
        for (int n = 0; n < 4; ++n) {
            float mx = acc[0][n][0];
#pragma unroll
            for (int m = 0; m < 8; ++m)
#pragma unroll
                for (int r = 0; r < 4; ++r) mx = fmaxf(mx, acc[m][n][r]);
            mx = fmaxf(mx, __shfl_xor(mx, 16));
            mx = fmaxf(mx, __shfl_xor(mx, 32));
            float sm = 0.f;
#pragma unroll
            for (int m = 0; m < 8; ++m)
#pragma unroll
                for (int r = 0; r < 4; ++r) sm += __expf(acc[m][n][r] - mx);
            sm += __shfl_xor(sm, 16);
            sm += __shfl_xor(sm, 32);
            if (lane < 16) {
                int c = cw * 64 + n * 16 + lane;
                redC[(h * 256 + c) * 2 + 0] = mx;
                redC[(h * 256 + c) * 2 + 1] = sm;
            }
        }
        __syncthreads();
        if (tid < 256) {
            float M = -1e30f, S = 0.f;
#pragma unroll
            for (int i = 0; i < 4; ++i) {
                float m_ = redR[(tid * 4 + i) * 2 + 0];
                float s_ = redR[(tid * 4 + i) * 2 + 1];
                float nm = fmaxf(M, m_);
                S = S * __expf(M - nm) + s_ * __expf(m_ - nm);
                M = nm;
            }
            rowP[(long)bx * PSTR + (long)bz * 512 + by * 256 + tid] = make_float2(M, S);
        } else {
            int c = tid - 256;
            float m0_ = redC[c * 2 + 0], s0_ = redC[c * 2 + 1];
            float m1_ = redC[(256 + c) * 2 + 0], s1_ = redC[(256 + c) * 2 + 1];
            float M = fmaxf(m0_, m1_);
            float S = s0_ * __expf(m0_ - M) + s1_ * __expf(m1_ - M);
            colP[(long)by * PSTR + (long)bz * 512 + bx * 256 + c] = make_float2(M, S);
        }
    } else {
        float* C = (float*)Cout + (long)bz * batchC;
        const float2* sp = scaleP + (long)bz * 512;
#pragma unroll
        for (int m = 0; m < 8; ++m)
#pragma unroll
            for (int r = 0; r < 4; ++r) {
                long row = row0 + m * 16 + r;
                float2 pa = sp[row], pb = sp[PSTR + row];
                float M = fmaxf(pa.x, pb.x);
                float S = pa.y * __expf(pa.x - M) + pb.y * __expf(pb.x - M);
                float inv = 1.0f / S;
#pragma unroll
                for (int n = 0; n < 4; ++n)
                    C[row * ldc + col0 + n * 16] = acc[m][n][r] * inv;
            }
    }
}

// ===========================================================================
// D1: cast q1 -> q1h + q1ht, and U -> Uht  (z<64: q1 tile; z==64: 2 U tiles)
// ===========================================================================
__global__ __launch_bounds__(256) void k_d1(const float* __restrict__ q1,
                                            f16* __restrict__ q1h, f16* __restrict__ q1ht,
                                            const float* __restrict__ U,
                                            f16* __restrict__ Uht) {
    __shared__ f16 tr[64][72];
    int tid = threadIdx.x;
    int z = blockIdx.z;
    if (z < 64) {
        int b = z;
        int d0 = blockIdx.x * 64, t0 = blockIdx.y * 64;
        const float* S = q1 + ((size_t)b * T_DIM + t0) * D_DIM + d0;
        f16* Dr = q1h + ((size_t)b * T_DIM + t0) * D_DIM + d0;
        int rr = tid >> 4, cc = (tid & 15) * 4;
#pragma unroll
        for (int i = 0; i < 4; ++i) {
            int r = rr + i * 16;
            float4 v = *(const float4*)(S + (size_t)r * D_DIM + cc);
            f16x4 h = {(f16)v.x, (f16)v.y, (f16)v.z, (f16)v.w};
            *(f16x4*)(Dr + (size_t)r * D_DIM + cc) = h;
            tr[cc + 0][r] = h[0];
            tr[cc + 1][r] = h[1];
            tr[cc + 2][r] = h[2];
            tr[cc + 3][r] = h[3];
        }
        __syncthreads();
        f16* Dt = q1ht + ((size_t)b * D_DIM + d0) * T_DIM + t0;
        int r2 = tid >> 3, c8 = (tid & 7) * 8;
#pragma unroll
        for (int i = 0; i < 2; ++i) {
            int d = r2 + i * 32;
            f16x8 vv = *(const f16x8*)(&tr[d][c8]);
            *(f16x8*)(Dt + (size_t)d * T_DIM + c8) = vv;
        }
    } else {
        int pos = blockIdx.y * 16 + blockIdx.x;   // 0..127
        for (int u = 0; u < 2; ++u) {
            int tile = pos + u * 128;             // 0..255
            int n0 = (tile & 15) * 64, k0 = (tile >> 4) * 64;
            int rr = tid >> 4, cc = (tid & 15) * 4;
#pragma unroll
            for (int i = 0; i < 4; ++i) {
                int r = rr + i * 16;
                float4 v = *(const float4*)(U + (size_t)(k0 + r) * D_DIM + n0 + cc);
                tr[cc + 0][r] = (f16)v.x;
                tr[cc + 1][r] = (f16)v.y;
                tr[cc + 2][r] = (f16)v.z;
                tr[cc + 3][r] = (f16)v.w;
            }
            __syncthreads();
            int r2 = tid >> 3, c8 = (tid & 7) * 8;
#pragma unroll
            for (int i = 0; i < 2; ++i) {
                int n = r2 + i * 32;
                f16x8 vv = *(const f16x8*)(&tr[n][c8]);
                *(f16x8*)(Uht + (size_t)(n0 + n) * D_DIM + k0 + c8) = vv;
            }
            __syncthreads();
        }
    }
}

// ===========================================================================
// D2: GEMM1 (qUh = q1h @ Uht^T, f16 out)  ||  cast q2 -> q2h + q2ht
// grid (4, 128 + 1024): by<128 -> GEMM block; else cast block (2 tiles/block)
// ===========================================================================
__global__ __launch_bounds__(512, 2) void k_d2(const f16* __restrict__ q1h,
                                               const f16* __restrict__ Uht,
                                               f16* __restrict__ qUh,
                                               const float* __restrict__ q2,
                                               f16* __restrict__ q2h,
                                               f16* __restrict__ q2ht) {
    __shared__ __align__(16) f16 SM[32768];   // 64KB union
    int tid = threadIdx.x;
    if (blockIdx.y < 128) {
        // ---------------- GEMM1 ----------------
        f16 (*LA)[8192] = (f16(*)[8192])SM;
        f16 (*LB)[8192] = (f16(*)[8192])(SM + 16384);
        const int lane = tid & 63, w = tid >> 6;
        int o = blockIdx.x + 4 * blockIdx.y;          // 0..511
        int fl = (o & 7) * 64 + (o >> 3);             // XCD swizzle, nwg=512
        int bx = fl & 3, by = fl >> 2;
        const f16* Ab = q1h + (long)(by * 256) * D_DIM;
        const f16* Bb = Uht + (long)(bx * 256) * D_DIM;

        const int r0 = tid >> 2, s0 = (tid & 3) ^ SWZ(r0);
        const int r1 = r0 + 128, s1 = (tid & 3) ^ SWZ(r1);
        const long offA0 = (long)r0 * D_DIM + s0 * 8;
        const long offA1 = (long)r1 * D_DIM + s1 * 8;
        const int ldsOff0 = w * 512, ldsOff1 = 4096 + w * 512;
        const int g = lane >> 4;
        const int rA0 = (w & 1) * 128 + (lane & 15);
        const int rB0 = (w >> 1) * 64 + (lane & 15);

        f32x4 acc[8][4] = {};
        gld_lds16(Ab + offA0, &LA[0][ldsOff0]);
        gld_lds16(Ab + offA1, &LA[0][ldsOff1]);
        gld_lds16(Bb + offA0, &LB[0][ldsOff0]);   // same offsets (ldb == lda)
        gld_lds16(Bb + offA1, &LB[0][ldsOff1]);
        __syncthreads();

        for (int t = 0; t < 32; ++t) {
            const int cur = t & 1;
            if (t + 1 < 32) {
                const long kt = (long)(t + 1) << 5;
                gld_lds16(Ab + offA0 + kt, &LA[cur ^ 1][ldsOff0]);
                gld_lds16(Ab + offA1 + kt, &LA[cur ^ 1][ldsOff1]);
                gld_lds16(Bb + offA0 + kt, &LB[cur ^ 1][ldsOff0]);
                gld_lds16(Bb + offA1 + kt, &LB[cur ^ 1][ldsOff1]);
            }
            f16x8 a[8], b[4];
#pragma unroll
            for (int m = 0; m < 8; ++m) {
                int r = rA0 + m * 16;
                a[m] = *(const f16x8*)(&LA[cur][r * 32 + ((g ^ SWZ(r)) << 3)]);
            }
#pragma unroll
            for (int n = 0; n < 4; ++n) {
                int r = rB0 + n * 16;
                b[n] = *(const f16x8*)(&LB[cur][r * 32 + ((g ^ SWZ(r)) << 3)]);
            }
            __builtin_amdgcn_s_setprio(1);
#pragma unroll
            for (int m = 0; m < 8; ++m)
#pragma unroll
                for (int n = 0; n < 4; ++n)
                    acc[m][n] = __builtin_amdgcn_mfma_f32_16x16x32_f16(a[m], b[n], acc[m][n], 0, 0, 0);
            __builtin_amdgcn_s_setprio(0);
            __syncthreads();
        }
        const int row0 = by * 256 + (w & 1) * 128 + (lane >> 4) * 4;
        const int col0 = bx * 256 + (w >> 1) * 64 + (lane & 15);
#pragma unroll
        for (int m = 0; m < 8; ++m)
#pragma unroll
            for (int r = 0; r < 4; ++r) {
                long row = row0 + m * 16 + r;
#pragma unroll
                for (int n = 0; n < 4; ++n)
                    qUh[row * D_DIM + col0 + n * 16] = (f16)acc[m][n][r];
            }
    } else {
        // ---------------- cast q2 (2 tiles per block, one per 256-thr half) --
        int hf = tid >> 8, t2 = tid & 255;
        f16 (*tr)[72] = (f16(*)[72])(SM + hf * 4608);
        int p = (blockIdx.y - 128) * 4 + blockIdx.x;  // 0..4095
        int tile = p * 2 + hf;                        // 0..8191
        int b = tile >> 7, rem = tile & 127;
        int d0 = (rem & 15) * 64, t0 = (rem >> 4) * 64;
        const float* S = q2 + ((size_t)b * T_DIM + t0) * D_DIM + d0;
        f16* Dr = q2h + ((size_t)b * T_DIM + t0) * D_DIM + d0;
        int rr = t2 >> 4, cc = (t2 & 15) * 4;
#pragma unroll
        for (int i = 0; i < 4; ++i) {
            int r = rr + i * 16;
            float4 v = *(const float4*)(S + (size_t)r * D_DIM + cc);
            f16x4 h = {(f16)v.x, (f16)v.y, (f16)v.z, (f16)v.w};
            *(f16x4*)(Dr + (size_t)r * D_DIM + cc) = h;
            tr[cc + 0][r] = h[0];
            tr[cc + 1][r] = h[1];
            tr[cc + 2][r] = h[2];
            tr[cc + 3][r] = h[3];
        }
        __syncthreads();
        f16* Dt = q2ht + ((size_t)b * D_DIM + d0) * T_DIM + t0;
        int r2 = t2 >> 3, c8 = (t2 & 7) * 8;
#pragma unroll
        for (int i = 0; i < 2; ++i) {
            int d = r2 + i * 32;
            f16x8 vv = *(const f16x8*)(&tr[d][c8]);
            *(f16x8*)(Dt + (size_t)d * T_DIM + c8) = vv;
        }
    }
}

// ===========================================================================
// D4: q2align (A = exp(att - rmax) inline, reg-staged)  ||  pconv -> P1h only
// grid (4, 2, 64 + 512): z<64 q2align; z>=64 pconv tile
// ===========================================================================
__global__ __launch_bounds__(512, 2) void k_d4(const float* __restrict__ att,
                                               const f16* __restrict__ q2ht,
                                               const float2* __restrict__ rowP,
                                               const float2* __restrict__ colP,
                                               float* __restrict__ out2,
                                               f16* __restrict__ P1h) {
    __shared__ __align__(16) f16 SM[33280];   // 64KB + 1KB (rmS)
    int tid = threadIdx.x;
    int z = blockIdx.z;
    if (z < 64) {
        // ---------------- q2align ----------------
        f16 (*LA)[8192] = (f16(*)[8192])SM;
        f16 (*LB)[8192] = (f16(*)[8192])(SM + 16384);
        float* rmS = (float*)(SM + 32768);    // 256 floats
        const int lane = tid & 63, w = tid >> 6;
        int o = blockIdx.x + 4 * blockIdx.y + 8 * z;  // 0..511
        int fl = (o & 7) * 64 + (o >> 3);             // XCD swizzle
        int bx = fl & 3, by = (fl >> 2) & 1, zb = fl >> 3;

        const float* Abase = att + (long)zb * TT + (long)(by * 256) * T_DIM;
        const f16* Bb = q2ht + (long)zb * TD + (long)(bx * 256) * T_DIM;

        if (tid < 256) {
            float2 pa = rowP[(long)zb * 512 + by * 256 + tid];
            float2 pb = rowP[PSTR + (long)zb * 512 + by * 256 + tid];
            rmS[tid] = fmaxf(pa.x, pb.x);
        }

        const int r0 = tid >> 2, j0 = tid & 3;
        const int r1 = r0 + 128;
        const int sb0 = j0 ^ SWZ(r0), sb1 = j0 ^ SWZ(r1);
        const long offB0 = (long)r0 * T_DIM + sb0 * 8;
        const long offB1 = (long)r1 * T_DIM + sb1 * 8;
        const int ldsOff0 = w * 512, ldsOff1 = 4096 + w * 512;
        const int wA0 = r0 * 32 + ((j0 ^ SWZ(r0)) << 3);
        const int wA1 = r1 * 32 + ((j0 ^ SWZ(r1)) << 3);
        const long srcA0 = (long)r0 * T_DIM + j0 * 8;
        const long srcA1 = (long)r1 * T_DIM + j0 * 8;

        const int g = lane >> 4;
        const int rA0 = (w & 1) * 128 + (lane & 15);
        const int rB0 = (w >> 1) * 64 + (lane & 15);

        __syncthreads();   // rmS ready
        const float m0 = rmS[r0], m1 = rmS[r1];

        f32x4 acc[8][4] = {};
        // prologue: A(0) reg-stage + B(0) gld_lds
        {
            float4 v0 = *(const float4*)(Abase + srcA0);
            float4 v1 = *(const float4*)(Abase + srcA0 + 4);
            float4 v2 = *(const float4*)(Abase + srcA1);
            float4 v3 = *(const float4*)(Abase + srcA1 + 4);
            f16x8 h0 = {(f16)__expf(v0.x - m0), (f16)__expf(v0.y - m0),
                        (f16)__expf(v0.z - m0), (f16)__expf(v0.w - m0),
                        (f16)__expf(v1.x - m0), (f16)__expf(v1.y - m0),
                        (f16)__expf(v1.z - m0), (f16)__expf(v1.w - m0)};
            f16x8 h1 = {(f16)__expf(v2.x - m1), (f16)__expf(v2.y - m1),
                        (f16)__expf(v2.z - m1), (f16)__expf(v2.w - m1),
                        (f16)__expf(v3.x - m1), (f16)__expf(v3.y - m1),
                        (f16)__expf(v3.z - m1), (f16)__expf(v3.w - m1)};
            *(f16x8*)(&LA[0][wA0]) = h0;
            *(f16x8*)(&LA[0][wA1]) = h1;
            gld_lds16(Bb + offB0, &LB[0][ldsOff0]);
            gld_lds16(Bb + offB1, &LB[0][ldsOff1]);
        }
        __syncthreads();

        for (int t = 0; t < 16; ++t) {
            const int cur = t & 1;
            float4 v0, v1, v2, v3;
            if (t + 1 < 16) {
                const long kc = (long)(t + 1) << 5;
                v0 = *(const float4*)(Abase + srcA0 + kc);
                v1 = *(const float4*)(Abase + srcA0 + kc + 4);
                v2 = *(const float4*)(Abase + srcA1 + kc);
                v3 = *(const float4*)(Abase + srcA1 + kc + 4);
                gld_lds16(Bb + offB0 + kc, &LB[cur ^ 1][ldsOff0]);
                gld_lds16(Bb + offB1 + kc, &LB[cur ^ 1][ldsOff1]);
            }
            f16x8 a[8], b[4];
#pragma unroll
            for (int m = 0; m < 8; ++m) {
                int r = rA0 + m * 16;
                a[m] = *(const f16x8*)(&LA[cur][r * 32 + ((g ^ SWZ(r)) << 3)]);
            }
#pragma unroll
            for (int n = 0; n < 4; ++n) {
                int r = rB0 + n * 16;
                b[n] = *(const f16x8*)(&LB[cur][r * 32 + ((g ^ SWZ(r)) << 3)]);
            }
            __builtin_amdgcn_s_setprio(1);
#pragma unroll
            for (int m = 0; m < 8; ++m)
#pragma unroll
                for (int n = 0; n < 4; ++n)
                    acc[m][n] = __builtin_amdgcn_mfma_f32_16x16x32_f16(a[m], b[n], acc[m][n], 0, 0, 0);
            __builtin_amdgcn_s_setprio(0);
            if (t + 1 < 16) {
                f16x8 h0 = {(f16)__expf(v0.x - m0), (f16)__expf(v0.y - m0),
                            (f16)__expf(v0.z - m0), (f16)__expf(v0.w - m0),
                            (f16)__expf(v1.x - m0), (f16)__expf(v1.y - m0),
                            (f16)__expf(v1.z - m0), (f16)__expf(v1.w - m0)};
                f16x8 h1 = {(f16)__expf(v2.x - m1), (f16)__expf(v2.y - m1),
                            (f16)__expf(v2.z - m1), (f16)__expf(v2.w - m1),
                            (f16)__expf(v3.x - m1), (f16)__expf(v3.y - m1),
                            (f16)__expf(v3.z - m1), (f16)__expf(v3.w - m1)};
                *(f16x8*)(&LA[cur ^ 1][wA0]) = h0;
                *(f16x8*)(&LA[cur ^ 1][wA1]) = h1;
            }
            __syncthreads();
        }

        const int row0 = by * 256 + (w & 1) * 128 + (lane >> 4) * 4;
        const int col0 = bx * 256 + (w >> 1) * 64 + (lane & 15);
        float* C = out2 + (long)zb * TD;
        const float2* sp = rowP + (long)zb * 512;
#pragma unroll
        for (int m = 0; m < 8; ++m)
#pragma unroll
            for (int r = 0; r < 4; ++r) {
                long row = row0 + m * 16 + r;
                float2 pa = sp[row], pb = sp[PSTR + row];
                float M = fmaxf(pa.x, pb.x);
                float S = pa.y * __expf(pa.x - M) + pb.y * __expf(pb.x - M);
                float inv = 1.0f / S;
#pragma unroll
                for (int n = 0; n < 4; ++n)
                    C[row * D_DIM + col0 + n * 16] = acc[m][n][r] * inv;
            }
    } else {
        // ---------------- pconv: P1h tile ----------------
        f16 (*tr)[72] = (f16(*)[72])SM;
        float* cmS = (float*)(SM + 16384);
        int id = (z - 64) * 8 + blockIdx.y * 4 + blockIdx.x;  // 0..4095
        int b = id >> 6, rem = id & 63;
        int t0 = (rem >> 3) * 64, s0 = (rem & 7) * 64;
        if (tid < 64) {
            float2 pa = colP[(long)b * 512 + s0 + tid];
            float2 pb = colP[PSTR + (long)b * 512 + s0 + tid];
            cmS[tid] = fmaxf(pa.x, pb.x);
        }
        __syncthreads();
        const float* S = att + (long)b * TT + (long)t0 * T_DIM + s0;
        int rr = tid >> 4, cc = (tid & 15) * 4;   // rr 0..31
#pragma unroll
        for (int i = 0; i < 2; ++i) {
            int r = rr + i * 32;
            float4 v = *(const float4*)(S + (long)r * T_DIM + cc);
            tr[cc + 0][r] = (f16)__expf(v.x - cmS[cc + 0]);
            tr[cc + 1][r] = (f16)__expf(v.y - cmS[cc + 1]);
            tr[cc + 2][r] = (f16)__expf(v.z - cmS[cc + 2]);
            tr[cc + 3][r] = (f16)__expf(v.w - cmS[cc + 3]);
        }
        __syncthreads();
        f16* Dt = P1h + (long)b * TT + (long)s0 * T_DIM + t0;
        int r2 = tid >> 3, c8 = (tid & 7) * 8;    // r2 0..63
        f16x8 vv = *(const f16x8*)(&tr[r2][c8]);
        *(f16x8*)(Dt + (long)r2 * T_DIM + c8) = vv;
    }
}

// ===========================================================================
extern "C" void kernel_launch(void* const* d_in, const int* in_sizes, int n_in,
                              void* d_out, int out_size, void* d_ws, size_t ws_size,
                              hipStream_t stream) {
    const float* q1 = (const float*)d_in[0];
    const float* q2 = (const float*)d_in[1];
    const float* U  = (const float*)d_in[2];
    float* out = (float*)d_out;

    const size_t BTD = (size_t)B_DIM * TD;   // 33.55M
    const size_t DD  = (size_t)D_DIM * D_DIM;
    const size_t BTT = (size_t)B_DIM * TT;   // 16.78M

    // ws layout (f16 unless noted)
    const size_t need = (5 * BTD + DD) * 2       // q1h,q1ht,q2h,q2ht,qUh + Uht
                      + BTT * 4                  // att f32
                      + BTT * 2                  // P1h
                      + 4 * (size_t)PSTR * sizeof(float2);   // rowP/colP [2][PSTR]
    if (need > ws_size) return;  // ws too small (never hit: harness gives ~0.5GB)

    f16* q1h  = (f16*)d_ws;
    f16* q1ht = q1h  + BTD;
    f16* q2h  = q1ht + BTD;
    f16* q2ht = q2h  + BTD;
    f16* Uht  = q2ht + BTD;
    f16* qUh  = Uht  + DD;
    float* att = (float*)(qUh + BTD);
    f16* P1h  = (f16*)(att + BTT);
    float2* rowP = (float2*)(P1h + BTT);   // [2][PSTR]
    float2* colP = rowP + 2 * (size_t)PSTR;

    // D1: cast q1 (+U)
    k_d1<<<dim3(16, 8, 65), 256, 0, stream>>>(q1, q1h, q1ht, U, Uht);
    // D2: GEMM1 || cast q2
    k_d2<<<dim3(4, 128 + 1024, 1), 512, 0, stream>>>(q1h, Uht, qUh, q2, q2h, q2ht);
    // D3: att = relu(qUh @ q2h^T) + softmax partials
    k_mfma2<1><<<dim3(2, 2, 64), 512, 0, stream>>>(
        qUh, D_DIM, q2h, D_DIM, D_DIM, att, T_DIM,
        nullptr, (long)TD, (long)TD, (long)TT, rowP, colP);
    // D4: q2align (output 1) || pconv -> P1h
    k_d4<<<dim3(4, 2, 64 + 512), 512, 0, stream>>>(
        att, q2ht, rowP, colP, out + BTD, P1h);
    // D5: q1align (output 0) = P1h @ q1ht^T * 1/csum
    k_mfma2<2><<<dim3(4, 2, 64), 512, 0, stream>>>(
        P1h, T_DIM, q1ht, T_DIM, T_DIM, out, D_DIM,
        colP, (long)TT, (long)TD, (long)TD, nullptr, nullptr);
}

// Round 7
// 387.563 us; speedup vs baseline: 1.1675x; 1.0888x over previous
//
#include <hip/hip_runtime.h>
#include <hip/hip_bf16.h>
#include <math.h>

#define B_DIM 64
#define T_DIM 512
#define D_DIM 1024
#define TT (T_DIM * T_DIM)   // 262144
#define TD (T_DIM * D_DIM)   // 524288
#define PSTR ((long)B_DIM * T_DIM)  // 32768: stride between the 2 softmax partials

typedef _Float16 f16;
typedef f16 f16x4 __attribute__((ext_vector_type(4)));
typedef f16 f16x8 __attribute__((ext_vector_type(8)));
typedef float f32x4 __attribute__((ext_vector_type(4)));

__device__ __forceinline__ void gld_lds16(const void* g, void* l) {
    __builtin_amdgcn_global_load_lds(
        (const __attribute__((address_space(1))) void*)g,
        (__attribute__((address_space(3))) void*)l, 16, 0, 0);
}

// LDS[r][j] holds global k-chunk (j ^ ((r>>1)&3)); conflict-free ds_read_b128.
#define SWZ(r) (((r) >> 1) & 3)

// ===========================================================================
// D1: cast q1 -> q1ht (transposed only), and U -> Uht
// ===========================================================================
__global__ __launch_bounds__(256) void k_d1(const float* __restrict__ q1,
                                            f16* __restrict__ q1ht,
                                            const float* __restrict__ U,
                                            f16* __restrict__ Uht) {
    __shared__ f16 tr[64][72];
    int tid = threadIdx.x;
    int z = blockIdx.z;
    if (z < 64) {
        int b = z;
        int d0 = blockIdx.x * 64, t0 = blockIdx.y * 64;
        const float* S = q1 + ((size_t)b * T_DIM + t0) * D_DIM + d0;
        int rr = tid >> 4, cc = (tid & 15) * 4;
#pragma unroll
        for (int i = 0; i < 4; ++i) {
            int r = rr + i * 16;
            float4 v = *(const float4*)(S + (size_t)r * D_DIM + cc);
            tr[cc + 0][r] = (f16)v.x;
            tr[cc + 1][r] = (f16)v.y;
            tr[cc + 2][r] = (f16)v.z;
            tr[cc + 3][r] = (f16)v.w;
        }
        __syncthreads();
        f16* Dt = q1ht + ((size_t)b * D_DIM + d0) * T_DIM + t0;
        int r2 = tid >> 3, c8 = (tid & 7) * 8;
#pragma unroll
        for (int i = 0; i < 2; ++i) {
            int d = r2 + i * 32;
            f16x8 vv = *(const f16x8*)(&tr[d][c8]);
            *(f16x8*)(Dt + (size_t)d * T_DIM + c8) = vv;
        }
    } else {
        int pos = blockIdx.y * 16 + blockIdx.x;   // 0..127
        for (int u = 0; u < 2; ++u) {
            int tile = pos + u * 128;             // 0..255
            int n0 = (tile & 15) * 64, k0 = (tile >> 4) * 64;
            int rr = tid >> 4, cc = (tid & 15) * 4;
#pragma unroll
            for (int i = 0; i < 4; ++i) {
                int r = rr + i * 16;
                float4 v = *(const float4*)(U + (size_t)(k0 + r) * D_DIM + n0 + cc);
                tr[cc + 0][r] = (f16)v.x;
                tr[cc + 1][r] = (f16)v.y;
                tr[cc + 2][r] = (f16)v.z;
                tr[cc + 3][r] = (f16)v.w;
            }
            __syncthreads();
            int r2 = tid >> 3, c8 = (tid & 7) * 8;
#pragma unroll
            for (int i = 0; i < 2; ++i) {
                int n = r2 + i * 32;
                f16x8 vv = *(const f16x8*)(&tr[n][c8]);
                *(f16x8*)(Uht + (size_t)(n0 + n) * D_DIM + k0 + c8) = vv;
            }
            __syncthreads();
        }
    }
}

// ===========================================================================
// D2: GEMM1 (qUh = cast(q1) @ Uht^T, A reg-staged from f32)  ||  cast q2
// grid (4, 128 + 1024): by<128 -> GEMM block; else cast block (2 tiles/block)
// ===========================================================================
__global__ __launch_bounds__(512, 2) void k_d2(const float* __restrict__ q1,
                                               const f16* __restrict__ Uht,
                                               f16* __restrict__ qUh,
                                               const float* __restrict__ q2,
                                               f16* __restrict__ q2h,
                                               f16* __restrict__ q2ht) {
    __shared__ __align__(16) f16 SM[32768];   // 64KB union
    int tid = threadIdx.x;
    if (blockIdx.y < 128) {
        // ---------------- GEMM1 ----------------
        f16 (*LA)[8192] = (f16(*)[8192])SM;
        f16 (*LB)[8192] = (f16(*)[8192])(SM + 16384);
        const int lane = tid & 63, w = tid >> 6;
        int o = blockIdx.x + 4 * blockIdx.y;          // 0..511
        int fl = (o & 7) * 64 + (o >> 3);             // XCD swizzle, nwg=512
        int bx = fl & 3, by = fl >> 2;
        const float* Aq = q1 + (long)(by * 256) * D_DIM;
        const f16* Bb = Uht + (long)(bx * 256) * D_DIM;

        const int r0 = tid >> 2, j0 = tid & 3;
        const int r1 = r0 + 128;
        const long srcA0 = (long)r0 * D_DIM + j0 * 8;
        const long srcA1 = (long)r1 * D_DIM + j0 * 8;
        const int wA0 = r0 * 32 + ((j0 ^ SWZ(r0)) << 3);
        const int wA1 = r1 * 32 + ((j0 ^ SWZ(r1)) << 3);
        const long offB0 = (long)r0 * D_DIM + (j0 ^ SWZ(r0)) * 8;
        const long offB1 = (long)r1 * D_DIM + (j0 ^ SWZ(r1)) * 8;
        const int ldsOff0 = w * 512, ldsOff1 = 4096 + w * 512;
        const int g = lane >> 4;
        const int rA0 = (w & 1) * 128 + (lane & 15);
        const int rB0 = (w >> 1) * 64 + (lane & 15);

        f32x4 acc[8][4] = {};
        {
            float4 v0 = *(const float4*)(Aq + srcA0);
            float4 v1 = *(const float4*)(Aq + srcA0 + 4);
            float4 v2 = *(const float4*)(Aq + srcA1);
            float4 v3 = *(const float4*)(Aq + srcA1 + 4);
            f16x8 h0 = {(f16)v0.x, (f16)v0.y, (f16)v0.z, (f16)v0.w,
                        (f16)v1.x, (f16)v1.y, (f16)v1.z, (f16)v1.w};
            f16x8 h1 = {(f16)v2.x, (f16)v2.y, (f16)v2.z, (f16)v2.w,
                        (f16)v3.x, (f16)v3.y, (f16)v3.z, (f16)v3.w};
            *(f16x8*)(&LA[0][wA0]) = h0;
            *(f16x8*)(&LA[0][wA1]) = h1;
            gld_lds16(Bb + offB0, &LB[0][ldsOff0]);
            gld_lds16(Bb + offB1, &LB[0][ldsOff1]);
        }
        __syncthreads();

        for (int t = 0; t < 32; ++t) {
            const int cur = t & 1;
            float4 v0, v1, v2, v3;
            if (t + 1 < 32) {
                const long kc = (long)(t + 1) << 5;
                v0 = *(const float4*)(Aq + srcA0 + kc);
                v1 = *(const float4*)(Aq + srcA0 + kc + 4);
                v2 = *(const float4*)(Aq + srcA1 + kc);
                v3 = *(const float4*)(Aq + srcA1 + kc + 4);
                gld_lds16(Bb + offB0 + kc, &LB[cur ^ 1][ldsOff0]);
                gld_lds16(Bb + offB1 + kc, &LB[cur ^ 1][ldsOff1]);
            }
            f16x8 a[8], b[4];
#pragma unroll
            for (int m = 0; m < 8; ++m) {
                int r = rA0 + m * 16;
                a[m] = *(const f16x8*)(&LA[cur][r * 32 + ((g ^ SWZ(r)) << 3)]);
            }
#pragma unroll
            for (int n = 0; n < 4; ++n) {
                int r = rB0 + n * 16;
                b[n] = *(const f16x8*)(&LB[cur][r * 32 + ((g ^ SWZ(r)) << 3)]);
            }
            __builtin_amdgcn_s_setprio(1);
#pragma unroll
            for (int m = 0; m < 8; ++m)
#pragma unroll
                for (int n = 0; n < 4; ++n)
                    acc[m][n] = __builtin_amdgcn_mfma_f32_16x16x32_f16(a[m], b[n], acc[m][n], 0, 0, 0);
            __builtin_amdgcn_s_setprio(0);
            if (t + 1 < 32) {
                f16x8 h0 = {(f16)v0.x, (f16)v0.y, (f16)v0.z, (f16)v0.w,
                            (f16)v1.x, (f16)v1.y, (f16)v1.z, (f16)v1.w};
                f16x8 h1 = {(f16)v2.x, (f16)v2.y, (f16)v2.z, (f16)v2.w,
                            (f16)v3.x, (f16)v3.y, (f16)v3.z, (f16)v3.w};
                *(f16x8*)(&LA[cur ^ 1][wA0]) = h0;
                *(f16x8*)(&LA[cur ^ 1][wA1]) = h1;
            }
            __syncthreads();
        }
        const int row0 = by * 256 + (w & 1) * 128 + (lane >> 4) * 4;
        const int col0 = bx * 256 + (w >> 1) * 64 + (lane & 15);
#pragma unroll
        for (int m = 0; m < 8; ++m)
#pragma unroll
            for (int r = 0; r < 4; ++r) {
                long row = row0 + m * 16 + r;
#pragma unroll
                for (int n = 0; n < 4; ++n)
                    qUh[row * D_DIM + col0 + n * 16] = (f16)acc[m][n][r];
            }
    } else {
        // ---------------- cast q2 (2 tiles per block) ----------------
        int hf = tid >> 8, t2 = tid & 255;
        f16 (*tr)[72] = (f16(*)[72])(SM + hf * 4608);
        int p = (blockIdx.y - 128) * 4 + blockIdx.x;  // 0..4095
        int tile = p * 2 + hf;                        // 0..8191
        int b = tile >> 7, rem = tile & 127;
        int d0 = (rem & 15) * 64, t0 = (rem >> 4) * 64;
        const float* S = q2 + ((size_t)b * T_DIM + t0) * D_DIM + d0;
        f16* Dr = q2h + ((size_t)b * T_DIM + t0) * D_DIM + d0;
        int rr = t2 >> 4, cc = (t2 & 15) * 4;
#pragma unroll
        for (int i = 0; i < 4; ++i) {
            int r = rr + i * 16;
            float4 v = *(const float4*)(S + (size_t)r * D_DIM + cc);
            f16x4 h = {(f16)v.x, (f16)v.y, (f16)v.z, (f16)v.w};
            *(f16x4*)(Dr + (size_t)r * D_DIM + cc) = h;
            tr[cc + 0][r] = h[0];
            tr[cc + 1][r] = h[1];
            tr[cc + 2][r] = h[2];
            tr[cc + 3][r] = h[3];
        }
        __syncthreads();
        f16* Dt = q2ht + ((size_t)b * D_DIM + d0) * T_DIM + t0;
        int r2 = t2 >> 3, c8 = (t2 & 7) * 8;
#pragma unroll
        for (int i = 0; i < 2; ++i) {
            int d = r2 + i * 32;
            f16x8 vv = *(const f16x8*)(&tr[d][c8]);
            *(f16x8*)(Dt + (size_t)d * T_DIM + c8) = vv;
        }
    }
}

// ===========================================================================
// D3: att GEMM (qUh @ q2h^T), relu'd in regs; epilogue emits
//   rowP/colP softmax partials AND P2'[t][s]=f16(exp(att-M_rowhalf)),
//   P1'[s][t]=f16(exp(att-M_colhalf)).  att f32 is never materialized.
// grid (2,2,64)
// ===========================================================================
__global__ __launch_bounds__(512, 2) void k_att3(const f16* __restrict__ qUh,
                                                 const f16* __restrict__ q2h,
                                                 f16* __restrict__ P2,
                                                 f16* __restrict__ P1,
                                                 float2* __restrict__ rowP,
                                                 float2* __restrict__ colP) {
    __shared__ __align__(16) f16 LA[2][8192];
    __shared__ __align__(16) f16 LB[2][8192];
    const int tid = threadIdx.x;
    const int lane = tid & 63, w = tid >> 6;

    int o = blockIdx.x + 2 * (blockIdx.y + 2 * blockIdx.z);  // nwg=256
    int fl = (o & 7) * 32 + (o >> 3);
    const int bx = fl & 1, by = (fl >> 1) & 1, zb = fl >> 2;

    const f16* Ab = qUh + (long)(zb * 512 + by * 256) * D_DIM;
    const f16* Bb = q2h + (long)zb * TD + (long)(bx * 256) * D_DIM;

    const int r0 = tid >> 2, j0 = tid & 3;
    const int r1 = r0 + 128;
    const long offA0 = (long)r0 * D_DIM + (j0 ^ SWZ(r0)) * 8;
    const long offA1 = (long)r1 * D_DIM + (j0 ^ SWZ(r1)) * 8;
    const int ldsOff0 = w * 512, ldsOff1 = 4096 + w * 512;
    const int g = lane >> 4;
    const int rA0 = (w & 1) * 128 + (lane & 15);
    const int rB0 = (w >> 1) * 64 + (lane & 15);

    f32x4 acc[8][4] = {};

    gld_lds16(Ab + offA0, &LA[0][ldsOff0]);
    gld_lds16(Ab + offA1, &LA[0][ldsOff1]);
    gld_lds16(Bb + offA0, &LB[0][ldsOff0]);
    gld_lds16(Bb + offA1, &LB[0][ldsOff1]);
    __syncthreads();

    for (int t = 0; t < 32; ++t) {
        const int cur = t & 1;
        if (t + 1 < 32) {
            const long kt = (long)(t + 1) << 5;
            gld_lds16(Ab + offA0 + kt, &LA[cur ^ 1][ldsOff0]);
            gld_lds16(Ab + offA1 + kt, &LA[cur ^ 1][ldsOff1]);
            gld_lds16(Bb + offA0 + kt, &LB[cur ^ 1][ldsOff0]);
            gld_lds16(Bb + offA1 + kt, &LB[cur ^ 1][ldsOff1]);
        }
        f16x8 a[8], b[4];
#pragma unroll
        for (int m = 0; m < 8; ++m) {
            int r = rA0 + m * 16;
            a[m] = *(const f16x8*)(&LA[cur][r * 32 + ((g ^ SWZ(r)) << 3)]);
        }
#pragma unroll
        for (int n = 0; n < 4; ++n) {
            int r = rB0 + n * 16;
            b[n] = *(const f16x8*)(&LB[cur][r * 32 + ((g ^ SWZ(r)) << 3)]);
        }
        __builtin_amdgcn_s_setprio(1);
#pragma unroll
        for (int m = 0; m < 8; ++m)
#pragma unroll
            for (int n = 0; n < 4; ++n)
                acc[m][n] = __builtin_amdgcn_mfma_f32_16x16x32_f16(a[m], b[n], acc[m][n], 0, 0, 0);
        __builtin_amdgcn_s_setprio(0);
        __syncthreads();
    }

    // relu
#pragma unroll
    for (int m = 0; m < 8; ++m)
#pragma unroll
        for (int n = 0; n < 4; ++n)
#pragma unroll
            for (int r = 0; r < 4; ++r)
                acc[m][n][r] = fmaxf(acc[m][n][r], 0.0f);

    // ---- softmax partials (LA reused as scratch) ----
    float* redR = (float*)(&LA[0][0]);   // [256][4][2]
    float* redC = redR + 2048;           // [2][256][2]
    float* rowM = redC + 1024;           // [256]
    float* colM = rowM + 256;            // [256]
    const int h = w & 1, cw = w >> 1;
#pragma unroll
    for (int m = 0; m < 8; ++m)
#pragma unroll
        for (int r = 0; r < 4; ++r) {
            float mx = fmaxf(fmaxf(acc[m][0][r], acc[m][1][r]),
                             fmaxf(acc[m][2][r], acc[m][3][r]));
            mx = fmaxf(mx, __shfl_xor(mx, 1));
            mx = fmaxf(mx, __shfl_xor(mx, 2));
            mx = fmaxf(mx, __shfl_xor(mx, 4));
            mx = fmaxf(mx, __shfl_xor(mx, 8));
            float sm = __expf(acc[m][0][r] - mx) + __expf(acc[m][1][r] - mx)
                     + __expf(acc[m][2][r] - mx) + __expf(acc[m][3][r] - mx);
            sm += __shfl_xor(sm, 1);
            sm += __shfl_xor(sm, 2);
            sm += __shfl_xor(sm, 4);
            sm += __shfl_xor(sm, 8);
            if ((lane & 15) == 0) {
                int lr = m * 16 + (lane >> 4) * 4 + r;
                redR[((h * 128 + lr) * 4 + cw) * 2 + 0] = mx;
                redR[((h * 128 + lr) * 4 + cw) * 2 + 1] = sm;
            }
        }
#pragma unroll
    for (int n = 0; n < 4; ++n) {
        float mx = acc[0][n][0];
#pragma unroll
        for (int m = 0; m < 8; ++m)
#pragma unroll
            for (int r = 0; r < 4; ++r) mx = fmaxf(mx, acc[m][n][r]);
        mx = fmaxf(mx, __shfl_xor(mx, 16));
        mx = fmaxf(mx, __shfl_xor(mx, 32));
        float sm = 0.f;
#pragma unroll
        for (int m = 0; m < 8; ++m)
#pragma unroll
            for (int r = 0; r < 4; ++r) sm += __expf(acc[m][n][r] - mx);
        sm += __shfl_xor(sm, 16);
        sm += __shfl_xor(sm, 32);
        if (lane < 16) {
            int c = cw * 64 + n * 16 + lane;
            redC[(h * 256 + c) * 2 + 0] = mx;
            redC[(h * 256 + c) * 2 + 1] = sm;
        }
    }
    __syncthreads();
    if (tid < 256) {
        float M = -1e30f, S = 0.f;
#pragma unroll
        for (int i = 0; i < 4; ++i) {
            float m_ = redR[(tid * 4 + i) * 2 + 0];
            float s_ = redR[(tid * 4 + i) * 2 + 1];
            float nm = fmaxf(M, m_);
            S = S * __expf(M - nm) + s_ * __expf(m_ - nm);
            M = nm;
        }
        rowP[(long)bx * PSTR + (long)zb * 512 + by * 256 + tid] = make_float2(M, S);
        rowM[tid] = M;
    } else {
        int c = tid - 256;
        float m0_ = redC[c * 2 + 0], s0_ = redC[c * 2 + 1];
        float m1_ = redC[(256 + c) * 2 + 0], s1_ = redC[(256 + c) * 2 + 1];
        float M = fmaxf(m0_, m1_);
        float S = s0_ * __expf(m0_ - M) + s1_ * __expf(m1_ - M);
        colP[(long)by * PSTR + (long)zb * 512 + bx * 256 + c] = make_float2(M, S);
        colM[c] = M;
    }
    __syncthreads();

    // ---- P2'[t][s] = f16(exp(att - M_rowhalf)) ----
    f16* P2b = P2 + (long)zb * TT;
#pragma unroll
    for (int m = 0; m < 8; ++m)
#pragma unroll
        for (int r = 0; r < 4; ++r) {
            int Lr = h * 128 + m * 16 + (lane >> 4) * 4 + r;
            float M = rowM[Lr];
            long base = (long)(by * 256 + Lr) * T_DIM + bx * 256;
#pragma unroll
            for (int n = 0; n < 4; ++n) {
                int c = cw * 64 + n * 16 + (lane & 15);
                P2b[base + c] = (f16)__expf(acc[m][n][r] - M);
            }
        }
    // ---- P1'[s][t] = f16(exp(att - M_colhalf)), 8B column stores ----
    f16* P1b = P1 + (long)zb * TT;
#pragma unroll
    for (int m = 0; m < 8; ++m) {
        int Lt = h * 128 + m * 16 + (lane >> 4) * 4;
#pragma unroll
        for (int n = 0; n < 4; ++n) {
            int Lc = cw * 64 + n * 16 + (lane & 15);
            float M = colM[Lc];
            f16x4 v = {(f16)__expf(acc[m][n][0] - M), (f16)__expf(acc[m][n][1] - M),
                       (f16)__expf(acc[m][n][2] - M), (f16)__expf(acc[m][n][3] - M)};
            *(f16x4*)(&P1b[(long)(bx * 256 + Lc) * T_DIM + by * 256 + Lt]) = v;
        }
    }
}

// ===========================================================================
// D4: both align GEMMs in one dispatch. z<64: q2align (P2', q2ht, rowP);
// z>=64: q1align (P1', q1ht, colP). A reg-staged f16 with rescale factor
// exp(M_half - M_global) per (row, k-half); epilogue * 1/S.
// grid (4,2,128)
// ===========================================================================
__global__ __launch_bounds__(512, 2) void k_align(
        const f16* __restrict__ P2, const f16* __restrict__ q2ht,
        const float2* __restrict__ rowP, float* __restrict__ outQ2,
        const f16* __restrict__ P1, const f16* __restrict__ q1ht,
        const float2* __restrict__ colP, float* __restrict__ outQ1) {
    __shared__ __align__(16) f16 LA[2][8192];
    __shared__ __align__(16) f16 LB[2][8192];
    const int tid = threadIdx.x;
    const int lane = tid & 63, w = tid >> 6;

    int o = blockIdx.x + 4 * (blockIdx.y + 2 * blockIdx.z);  // nwg=1024
    int fl = (o & 7) * 128 + (o >> 3);
    const int bx = fl & 3, by = (fl >> 2) & 1, z = fl >> 3;
    const int zb = z & 63;

    const f16* P  = (z < 64) ? P2 : P1;
    const f16* Bt = (z < 64) ? q2ht : q1ht;
    const float2* sp = ((z < 64) ? rowP : colP) + (long)zb * 512;
    float* out = ((z < 64) ? outQ2 : outQ1) + (long)zb * TD;

    const f16* Ab = P + (long)zb * TT + (long)(by * 256) * T_DIM;
    const f16* Bb = Bt + (long)zb * TD + (long)(bx * 256) * T_DIM;

    const int r0 = tid >> 2, j0 = tid & 3;
    const int r1 = r0 + 128;
    // rescale factors: fac(r, k-half) = exp(M_half - M_global)
    float2 pa0 = sp[by * 256 + r0], pb0 = sp[PSTR + by * 256 + r0];
    float M0 = fmaxf(pa0.x, pb0.x);
    f16 f00 = (f16)__expf(pa0.x - M0), f01 = (f16)__expf(pb0.x - M0);
    float2 pa1 = sp[by * 256 + r1], pb1 = sp[PSTR + by * 256 + r1];
    float M1 = fmaxf(pa1.x, pb1.x);
    f16 f10 = (f16)__expf(pa1.x - M1), f11 = (f16)__expf(pb1.x - M1);

    const long srcA0 = (long)r0 * T_DIM + j0 * 8;
    const long srcA1 = (long)r1 * T_DIM + j0 * 8;
    const int wA0 = r0 * 32 + ((j0 ^ SWZ(r0)) << 3);
    const int wA1 = r1 * 32 + ((j0 ^ SWZ(r1)) << 3);
    const long offB0 = (long)r0 * T_DIM + (j0 ^ SWZ(r0)) * 8;
    const long offB1 = (long)r1 * T_DIM + (j0 ^ SWZ(r1)) * 8;
    const int ldsOff0 = w * 512, ldsOff1 = 4096 + w * 512;
    const int g = lane >> 4;
    const int rA0 = (w & 1) * 128 + (lane & 15);
    const int rB0 = (w >> 1) * 64 + (lane & 15);

    f32x4 acc[8][4] = {};
    {
        f16x8 a0 = *(const f16x8*)(Ab + srcA0);
        f16x8 a1 = *(const f16x8*)(Ab + srcA1);
#pragma unroll
        for (int i = 0; i < 8; ++i) { a0[i] *= f00; a1[i] *= f10; }
        *(f16x8*)(&LA[0][wA0]) = a0;
        *(f16x8*)(&LA[0][wA1]) = a1;
        gld_lds16(Bb + offB0, &LB[0][ldsOff0]);
        gld_lds16(Bb + offB1, &LB[0][ldsOff1]);
    }
    __syncthreads();

    for (int t = 0; t < 16; ++t) {
        const int cur = t & 1;
        f16x8 a0n, a1n;
        if (t + 1 < 16) {
            const long kc = (long)(t + 1) << 5;
            a0n = *(const f16x8*)(Ab + srcA0 + kc);
            a1n = *(const f16x8*)(Ab + srcA1 + kc);
            gld_lds16(Bb + offB0 + kc, &LB[cur ^ 1][ldsOff0]);
            gld_lds16(Bb + offB1 + kc, &LB[cur ^ 1][ldsOff1]);
        }
        f16x8 a[8], b[4];
#pragma unroll
        for (int m = 0; m < 8; ++m) {
            int r = rA0 + m * 16;
            a[m] = *(const f16x8*)(&LA[cur][r * 32 + ((g ^ SWZ(r)) << 3)]);
        }
#pragma unroll
        for (int n = 0; n < 4; ++n) {
            int r = rB0 + n * 16;
            b[n] = *(const f16x8*)(&LB[cur][r * 32 + ((g ^ SWZ(r)) << 3)]);
        }
        __builtin_amdgcn_s_setprio(1);
#pragma unroll
        for (int m = 0; m < 8; ++m)
#pragma unroll
            for (int n = 0; n < 4; ++n)
                acc[m][n] = __builtin_amdgcn_mfma_f32_16x16x32_f16(a[m], b[n], acc[m][n], 0, 0, 0);
        __builtin_amdgcn_s_setprio(0);
        if (t + 1 < 16) {
            f16 fa = ((t + 1) & 8) ? f01 : f00;
            f16 fb = ((t + 1) & 8) ? f11 : f10;
#pragma unroll
            for (int i = 0; i < 8; ++i) { a0n[i] *= fa; a1n[i] *= fb; }
            *(f16x8*)(&LA[cur ^ 1][wA0]) = a0n;
            *(f16x8*)(&LA[cur ^ 1][wA1]) = a1n;
        }
        __syncthreads();
    }

    const int row0 = by * 256 + (w & 1) * 128 + (lane >> 4) * 4;
    const int col0 = bx * 256 + (w >> 1) * 64 + (lane & 15);
#pragma unroll
    for (int m = 0; m < 8; ++m)
#pragma unroll
        for (int r = 0; r < 4; ++r) {
            int row = row0 + m * 16 + r;
            float2 pa = sp[row], pb = sp[PSTR + row];
            float M = fmaxf(pa.x, pb.x);
            float S = pa.y * __expf(pa.x - M) + pb.y * __expf(pb.x - M);
            float inv = 1.0f / S;
#pragma unroll
            for (int n = 0; n < 4; ++n)
                out[(long)row * D_DIM + col0 + n * 16] = acc[m][n][r] * inv;
        }
}

// ===========================================================================
extern "C" void kernel_launch(void* const* d_in, const int* in_sizes, int n_in,
                              void* d_out, int out_size, void* d_ws, size_t ws_size,
                              hipStream_t stream) {
    const float* q1 = (const float*)d_in[0];
    const float* q2 = (const float*)d_in[1];
    const float* U  = (const float*)d_in[2];
    float* out = (float*)d_out;

    const size_t BTD = (size_t)B_DIM * TD;   // 33.55M
    const size_t DD  = (size_t)D_DIM * D_DIM;
    const size_t BTT = (size_t)B_DIM * TT;   // 16.78M

    const size_t need = (4 * BTD + DD) * 2      // q1ht,q2h,q2ht,qUh + Uht
                      + 2 * BTT * 2             // P2', P1'
                      + 4 * (size_t)PSTR * sizeof(float2);
    if (need > ws_size) return;

    f16* q1ht = (f16*)d_ws;
    f16* q2h  = q1ht + BTD;
    f16* q2ht = q2h  + BTD;
    f16* Uht  = q2ht + BTD;
    f16* qUh  = Uht  + DD;
    f16* P2   = qUh  + BTD;
    f16* P1   = P2   + BTT;
    float2* rowP = (float2*)(P1 + BTT);   // [2][PSTR]
    float2* colP = rowP + 2 * (size_t)PSTR;

    // D1: cast q1 -> q1ht, U -> Uht
    k_d1<<<dim3(16, 8, 65), 256, 0, stream>>>(q1, q1ht, U, Uht);
    // D2: GEMM1 (A from q1 f32) || cast q2 -> q2h,q2ht
    k_d2<<<dim3(4, 128 + 1024, 1), 512, 0, stream>>>(q1, Uht, qUh, q2, q2h, q2ht);
    // D3: att GEMM -> partials + P2' + P1' (no att f32)
    k_att3<<<dim3(2, 2, 64), 512, 0, stream>>>(qUh, q2h, P2, P1, rowP, colP);
    // D4: both align GEMMs
    k_align<<<dim3(4, 2, 128), 512, 0, stream>>>(
        P2, q2ht, rowP, out + BTD, P1, q1ht, colP, out);
}